// Round 5
// baseline (185.496 us; speedup 1.0000x reference)
//
#include <hip/hip_runtime.h>
#include <hip/hip_bf16.h>
#include <stdint.h>

// B=131072, T=8, E=16, V=29. f32 in / f32 out (proven round 4).
// g_tab layout (word offsets, all float4-friendly):
//   QTT [29][32] @0      (a*32+c)        928
//   QTP [29][8]  @928    (a*8+u)         232
//   QPT [8][32]  @1160   (t*32+c)        256
//   QPP [8][8]   @1416   (t*8+u)          64
//   bias[32]     @1480                    32
//   LM  [29]a    @1512   a*260 + u*32 + v (260 = 8*32+4: a*260 % 32 = a*4 -> 8
//                        bank-groups x 4 banks = full spread for b128 gathers)
//   total 9052 -> pad 9056 words (36224 B) = 2264 float4
#define NVOC 29
#define TABW 9056

__device__ __attribute__((aligned(16))) float g_tab[TABW];

__device__ __forceinline__ float b2f(__hip_bfloat16 v) { return __bfloat162float(v); }
__device__ __forceinline__ float ldin(const void* p, int i, bool isf32) {
    return isf32 ? ((const float*)p)[i] : b2f(((const __hip_bfloat16*)p)[i]);
}

// ---------------- Kernel A: build tables once into g_tab ----------------
__global__ void prep_kernel(const void* __restrict__ tok, const void* __restrict__ pos,
                            const void* __restrict__ Wk,  const void* __restrict__ Wq,
                            const void* __restrict__ Wv,  const void* __restrict__ lmW,
                            const void* __restrict__ lmb) {
    __shared__ float sTQ[29][17], sTK[29][17], sTV[29][17];
    __shared__ float sPQ[8][17],  sPK[8][17],  sPV[8][17];
    __shared__ float sLW[29][17];
    const int tid = threadIdx.x;

    // input dtype sniff (insurance; inputs proven f32)
    const uint32_t* tw = (const uint32_t*)tok;
    int cnt = 0;
    #pragma unroll
    for (int wi = 0; wi < 32; ++wi) {
        uint32_t x = tw[wi];
        uint32_t e0 = (x >> 7) & 0xFF, e1 = (x >> 23) & 0xFF;
        cnt += (e0 >= 96 && e0 <= 132) ? 1 : 0;
        cnt += (e1 >= 96 && e1 <= 132) ? 1 : 0;
    }
    const bool isf32 = (cnt < 54);

    for (int i = tid; i < 29 * 16; i += 256) sLW[i >> 4][i & 15] = ldin(lmW, i, isf32);

    for (int i = tid; i < 111 * 16; i += 256) {
        const int h = i & 15, rt = i >> 4;
        const void* xp; int xo; const void* wp; float* dst;
        if (rt < 29)       { xp = tok; xo = rt * 16;         wp = Wq; dst = &sTQ[rt][h]; }
        else if (rt < 58)  { xp = tok; xo = (rt - 29) * 16;  wp = Wk; dst = &sTK[rt - 29][h]; }
        else if (rt < 87)  { xp = tok; xo = (rt - 58) * 16;  wp = Wv; dst = &sTV[rt - 58][h]; }
        else if (rt < 95)  { xp = pos; xo = (rt - 87) * 16;  wp = Wq; dst = &sPQ[rt - 87][h]; }
        else if (rt < 103) { xp = pos; xo = (rt - 95) * 16;  wp = Wk; dst = &sPK[rt - 95][h]; }
        else               { xp = pos; xo = (rt - 103) * 16; wp = Wv; dst = &sPV[rt - 103][h]; }
        float s = 0.f;
        #pragma unroll
        for (int e = 0; e < 16; ++e)
            s += ldin(xp, xo + e, isf32) * ldin(wp, h * 16 + e, isf32);
        *dst = s;
    }
    __syncthreads();

    const float f = 0.25f * 1.44269504088896340736f;  // scale * log2(e)

    for (int g = blockIdx.x * 256 + tid; g < TABW; g += gridDim.x * 256) {
        float val = 0.f;
        if (g < 928) {                       // QTT [29][32]
            int a = g >> 5, c = g & 31;
            if (c < 29) { float s = 0.f;
                #pragma unroll
                for (int h = 0; h < 16; ++h) s += sTQ[a][h] * sTK[c][h];
                val = f * s; }
        } else if (g < 1160) {               // QTP [29][8]
            int o = g - 928, a = o >> 3, u = o & 7; float s = 0.f;
            #pragma unroll
            for (int h = 0; h < 16; ++h) s += sTQ[a][h] * sPK[u][h];
            val = f * s;
        } else if (g < 1416) {               // QPT [8][32]
            int o = g - 1160, t = o >> 5, c = o & 31;
            if (c < 29) { float s = 0.f;
                #pragma unroll
                for (int h = 0; h < 16; ++h) s += sPQ[t][h] * sTK[c][h];
                val = f * s; }
        } else if (g < 1480) {               // QPP [8][8]
            int o = g - 1416, t = o >> 3, u = o & 7; float s = 0.f;
            #pragma unroll
            for (int h = 0; h < 16; ++h) s += sPQ[t][h] * sPK[u][h];
            val = f * s;
        } else if (g < 1512) {               // bias [32]
            int v = g - 1480;
            if (v < NVOC) val = ldin(lmb, v, isf32);
        } else if (g < 1512 + 29 * 260) {    // LM
            int o = g - 1512, a = o / 260, r = o % 260;
            if (r < 256) {
                int u = r >> 5, v = r & 31;
                if (v < NVOC) { float s = 0.f;
                    #pragma unroll
                    for (int h = 0; h < 16; ++h) s += (sTV[a][h] + sPV[u][h]) * sLW[v][h];
                    val = s; }
            }
        }
        g_tab[g] = val;
    }
}

// ---------------- Kernel B ----------------
// 64 batches x 8 timesteps per block; t = tid>>6 wave-uniform (exact causal trips).
// LDS union: tables (9056 w) then half-block output staging (256 rows x 32,
// rotation-swizzled (v+lb)&31 -> conflict-free writes AND reads).
__global__ __launch_bounds__(512, 6)
void main_kernel(const int* __restrict__ idxg, float* __restrict__ out) {
    __shared__ __attribute__((aligned(16))) float s[TABW];   // 36224 B
    float4* s4 = (float4*)s;

    const int tid = threadIdx.x;
    const int blk = blockIdx.x;
    const int t  = tid >> 6;
    const int lb = tid & 63;

    // idx straight from global, 2x int4 per thread (waves redundant -> L1 hit)
    const int4* ig = (const int4*)(idxg + (size_t)blk * 512);
    const int4 iA = ig[lb * 2], iB = ig[lb * 2 + 1];

    // stage tables as float4
    const float4* gt4 = (const float4*)g_tab;
    for (int i = tid; i < TABW / 4; i += 512) s4[i] = gt4[i];
    __syncthreads();

    const int iu[8] = { iA.x, iA.y, iA.z, iA.w, iB.x, iB.y, iB.z, iB.w };
    const int it = (t == 0) ? iu[0] : (t == 1) ? iu[1] : (t == 2) ? iu[2] :
                   (t == 3) ? iu[3] : (t == 4) ? iu[4] : (t == 5) ? iu[5] :
                   (t == 6) ? iu[6] : iu[7];

    // scores: QTP row (2 b128), QPP row (broadcast b128), QTT/QPT scalar gathers
    const float4 qtpA = s4[232 + it * 2], qtpB = s4[233 + it * 2];
    const float4 qppA = s4[354 + t * 2],  qppB = s4[355 + t * 2];
    const float qtp[8] = { qtpA.x, qtpA.y, qtpA.z, qtpA.w, qtpB.x, qtpB.y, qtpB.z, qtpB.w };
    const float qpp[8] = { qppA.x, qppA.y, qppA.z, qppA.w, qppB.x, qppB.y, qppB.z, qppB.w };

    float w[8];
    #pragma unroll
    for (int u = 0; u < 8; ++u) {
        float wu = s[it * 32 + iu[u]] + qtp[u]
                 + s[1160 + t * 32 + iu[u]] + qpp[u];
        w[u] = (u <= t) ? wu : -1.0e30f;     // exp2(-1e30) == 0
    }
    float mx = w[0];
    #pragma unroll
    for (int u = 1; u < 8; ++u) mx = fmaxf(mx, w[u]);
    float ssum = 0.f;
    #pragma unroll
    for (int u = 0; u < 8; ++u) { float e = exp2f(w[u] - mx); w[u] = e; ssum += e; }
    const float inv = 1.0f / ssum;

    // PV gather: (t+1) x 8 ds_read_b128, a-stride 260 -> near-ideal bank spread
    float4 acc[8];
    #pragma unroll
    for (int j = 0; j < 8; ++j) acc[j] = make_float4(0.f, 0.f, 0.f, 0.f);
    #pragma unroll
    for (int u = 0; u < 8; ++u) if (u <= t) {        // wave-uniform trips
        const float pu = w[u];
        const float4* r = s4 + 378 + iu[u] * 65 + u * 8;   // (1512 + iu*260 + u*32)/4
        #pragma unroll
        for (int j = 0; j < 8; ++j) {
            float4 m = r[j];
            acc[j].x = fmaf(pu, m.x, acc[j].x);
            acc[j].y = fmaf(pu, m.y, acc[j].y);
            acc[j].z = fmaf(pu, m.z, acc[j].z);
            acc[j].w = fmaf(pu, m.w, acc[j].w);
        }
    }
    // finalize: logits = acc*inv + bias (bias b128 broadcast)
    #pragma unroll
    for (int j = 0; j < 8; ++j) {
        float4 b = s4[370 + j];
        acc[j].x = fmaf(acc[j].x, inv, b.x);
        acc[j].y = fmaf(acc[j].y, inv, b.y);
        acc[j].z = fmaf(acc[j].z, inv, b.z);
        acc[j].w = fmaf(acc[j].w, inv, b.w);
    }

    // two-round staging + coalesced store (rows of 32, rotation (v+lb)&31)
    #pragma unroll
    for (int h = 0; h < 2; ++h) {
        __syncthreads();              // h=0: tables dead; h=1: prev copy done
        if ((t >> 2) == h) {
            const int rbase = (lb * 4 + (t & 3)) * 32;
            #pragma unroll
            for (int j = 0; j < 8; ++j) {
                s[rbase + ((4 * j + 0 + lb) & 31)] = acc[j].x;
                if (4 * j + 1 < NVOC) s[rbase + ((4 * j + 1 + lb) & 31)] = acc[j].y;
                if (4 * j + 2 < NVOC) s[rbase + ((4 * j + 2 + lb) & 31)] = acc[j].z;
                if (4 * j + 3 < NVOC) s[rbase + ((4 * j + 3 + lb) & 31)] = acc[j].w;
            }
        }
        __syncthreads();
        // copy half-slab: rows (lb,tt=t&3) -> out[(lb*8 + h*4+tt)*29 + v]
        float* ob = out + (size_t)blk * (512 * NVOC) + h * 116;
        for (int i = tid; i < 256 * NVOC; i += 512) {
            int lbg = i / 116; int rr = i - lbg * 116;
            int ttg = rr / 29; int vg = rr - ttg * 29;
            ob[lbg * 232 + ttg * 29 + vg] = s[(lbg * 4 + ttg) * 32 + ((vg + lbg) & 31)];
        }
    }
}

extern "C" void kernel_launch(void* const* d_in, const int* in_sizes, int n_in,
                              void* d_out, int out_size, void* d_ws, size_t ws_size,
                              hipStream_t stream) {
    const int* idx = (const int*)d_in[0];
    const void* tok = d_in[1];
    const void* pos = d_in[2];
    const void* Wk  = d_in[3];
    const void* Wq  = d_in[4];
    const void* Wv  = d_in[5];
    const void* lmW = d_in[6];
    const void* lmb = d_in[7];
    float* out = (float*)d_out;

    const int B = in_sizes[0] / 8;              // 131072
    const int nblk = B / 64;                    // 2048

    hipLaunchKernelGGL(prep_kernel, dim3(16), dim3(256), 0, stream,
                       tok, pos, Wk, Wq, Wv, lmW, lmb);
    hipLaunchKernelGGL(main_kernel, dim3(nblk), dim3(512), 0, stream,
                       idx, out);
}

// Round 6
// 168.211 us; speedup vs baseline: 1.1028x; 1.1028x over previous
//
#include <hip/hip_runtime.h>
#include <hip/hip_bf16.h>
#include <stdint.h>

// B=131072, T=8, E=16, V=29. f32 in / f32 out (proven round 4).
// g_tab layout (word offsets, float4-friendly):
//   QTT [29][32] @0      (a*32+c)
//   QTP [29][8]  @928    (a*8+u)
//   QPT [8][32]  @1160   (t*32+c)
//   QPP [8][8]   @1416   (t*8+u)
//   bias[32]     @1480
//   LM  [29]     @1512   a*260 + u*32 + v   (260%32=4 -> iu spreads 8 bank-groups)
//   total 9052 -> pad 9056 words
#define NVOC 29
#define TABW 9056

__device__ __attribute__((aligned(16))) float g_tab[TABW];

__device__ __forceinline__ float b2f(__hip_bfloat16 v) { return __bfloat162float(v); }
__device__ __forceinline__ float ldin(const void* p, int i, bool isf32) {
    return isf32 ? ((const float*)p)[i] : b2f(((const __hip_bfloat16*)p)[i]);
}

// ---------------- Kernel A: build tables once into g_tab ----------------
__global__ void prep_kernel(const void* __restrict__ tok, const void* __restrict__ pos,
                            const void* __restrict__ Wk,  const void* __restrict__ Wq,
                            const void* __restrict__ Wv,  const void* __restrict__ lmW,
                            const void* __restrict__ lmb) {
    __shared__ float sTQ[29][17], sTK[29][17], sTV[29][17];
    __shared__ float sPQ[8][17],  sPK[8][17],  sPV[8][17];
    __shared__ float sLW[29][17];
    const int tid = threadIdx.x;

    // input dtype sniff (insurance; inputs proven f32)
    const uint32_t* tw = (const uint32_t*)tok;
    int cnt = 0;
    #pragma unroll
    for (int wi = 0; wi < 32; ++wi) {
        uint32_t x = tw[wi];
        uint32_t e0 = (x >> 7) & 0xFF, e1 = (x >> 23) & 0xFF;
        cnt += (e0 >= 96 && e0 <= 132) ? 1 : 0;
        cnt += (e1 >= 96 && e1 <= 132) ? 1 : 0;
    }
    const bool isf32 = (cnt < 54);

    for (int i = tid; i < 29 * 16; i += 256) sLW[i >> 4][i & 15] = ldin(lmW, i, isf32);

    for (int i = tid; i < 111 * 16; i += 256) {
        const int h = i & 15, rt = i >> 4;
        const void* xp; int xo; const void* wp; float* dst;
        if (rt < 29)       { xp = tok; xo = rt * 16;         wp = Wq; dst = &sTQ[rt][h]; }
        else if (rt < 58)  { xp = tok; xo = (rt - 29) * 16;  wp = Wk; dst = &sTK[rt - 29][h]; }
        else if (rt < 87)  { xp = tok; xo = (rt - 58) * 16;  wp = Wv; dst = &sTV[rt - 58][h]; }
        else if (rt < 95)  { xp = pos; xo = (rt - 87) * 16;  wp = Wq; dst = &sPQ[rt - 87][h]; }
        else if (rt < 103) { xp = pos; xo = (rt - 95) * 16;  wp = Wk; dst = &sPK[rt - 95][h]; }
        else               { xp = pos; xo = (rt - 103) * 16; wp = Wv; dst = &sPV[rt - 103][h]; }
        float s = 0.f;
        #pragma unroll
        for (int e = 0; e < 16; ++e)
            s += ldin(xp, xo + e, isf32) * ldin(wp, h * 16 + e, isf32);
        *dst = s;
    }
    __syncthreads();

    const float f = 0.25f * 1.44269504088896340736f;  // scale * log2(e)

    for (int g = blockIdx.x * 256 + tid; g < TABW; g += gridDim.x * 256) {
        float val = 0.f;
        if (g < 928) {                       // QTT [29][32]
            int a = g >> 5, c = g & 31;
            if (c < 29) { float s = 0.f;
                #pragma unroll
                for (int h = 0; h < 16; ++h) s += sTQ[a][h] * sTK[c][h];
                val = f * s; }
        } else if (g < 1160) {               // QTP [29][8]
            int o = g - 928, a = o >> 3, u = o & 7; float s = 0.f;
            #pragma unroll
            for (int h = 0; h < 16; ++h) s += sTQ[a][h] * sPK[u][h];
            val = f * s;
        } else if (g < 1416) {               // QPT [8][32]
            int o = g - 1160, t = o >> 5, c = o & 31;
            if (c < 29) { float s = 0.f;
                #pragma unroll
                for (int h = 0; h < 16; ++h) s += sPQ[t][h] * sTK[c][h];
                val = f * s; }
        } else if (g < 1480) {               // QPP [8][8]
            int o = g - 1416, t = o >> 3, u = o & 7; float s = 0.f;
            #pragma unroll
            for (int h = 0; h < 16; ++h) s += sPQ[t][h] * sPK[u][h];
            val = f * s;
        } else if (g < 1512) {               // bias [32]
            int v = g - 1480;
            if (v < NVOC) val = ldin(lmb, v, isf32);
        } else if (g < 1512 + 29 * 260) {    // LM
            int o = g - 1512, a = o / 260, r = o % 260;
            if (r < 256) {
                int u = r >> 5, v = r & 31;
                if (v < NVOC) { float s = 0.f;
                    #pragma unroll
                    for (int h = 0; h < 16; ++h) s += (sTV[a][h] + sPV[u][h]) * sLW[v][h];
                    val = s; }
            }
        }
        g_tab[g] = val;
    }
}

// ---------------- Kernel B ----------------
// 64 batches x 8 t's per block; t = tid>>6 wave-uniform (exact causal trips).
// LDS: one 16384-word union buffer. Phase 1: tables (first 9056 w).
// Phase 2: 512 output rows x 32 w, float4-group rotation (j+lb)&7 -> b128
// writes at the 8-words/bank theoretical minimum, zero conflicts.
// __launch_bounds__(512,4): 128-VGPR budget, NO spills (round-5 lesson: (512,6)
// forced <=85 VGPR -> scratch spills in the PV loop ate the entire gain).
__global__ __launch_bounds__(512, 4)
void main_kernel(const int* __restrict__ idxg, float* __restrict__ out) {
    __shared__ __attribute__((aligned(16))) float s[16384];   // 65536 B -> 2 blk/CU
    float4* s4 = (float4*)s;

    const int tid = threadIdx.x;
    const int blk = blockIdx.x;
    const int t  = tid >> 6;
    const int lb = tid & 63;

    // idx direct from global: 2x int4/thread (8 waves hit same 2 KB -> L1)
    const int4* ig = (const int4*)(idxg + (size_t)blk * 512);
    const int4 iA = ig[lb * 2], iB = ig[lb * 2 + 1];

    // stage tables as float4
    const float4* gt4 = (const float4*)g_tab;
    for (int i = tid; i < TABW / 4; i += 512) s4[i] = gt4[i];
    __syncthreads();

    const int iu[8] = { iA.x, iA.y, iA.z, iA.w, iB.x, iB.y, iB.z, iB.w };
    const int it = (t == 0) ? iu[0] : (t == 1) ? iu[1] : (t == 2) ? iu[2] :
                   (t == 3) ? iu[3] : (t == 4) ? iu[4] : (t == 5) ? iu[5] :
                   (t == 6) ? iu[6] : iu[7];

    // scores: QTP row (2 b128), QPP row (2 b128 bcast), QTT/QPT scalar gathers
    const float4 qtpA = s4[232 + it * 2], qtpB = s4[233 + it * 2];
    const float4 qppA = s4[354 + t * 2],  qppB = s4[355 + t * 2];
    const float qtp[8] = { qtpA.x, qtpA.y, qtpA.z, qtpA.w, qtpB.x, qtpB.y, qtpB.z, qtpB.w };
    const float qpp[8] = { qppA.x, qppA.y, qppA.z, qppA.w, qppB.x, qppB.y, qppB.z, qppB.w };

    float w[8];
    #pragma unroll
    for (int u = 0; u < 8; ++u) {
        float wu = s[it * 32 + iu[u]] + qtp[u]
                 + s[1160 + t * 32 + iu[u]] + qpp[u];
        w[u] = (u <= t) ? wu : -1.0e30f;     // exp2(-1e30) == 0
    }
    float mx = w[0];
    #pragma unroll
    for (int u = 1; u < 8; ++u) mx = fmaxf(mx, w[u]);
    float ssum = 0.f;
    #pragma unroll
    for (int u = 0; u < 8; ++u) { float e = exp2f(w[u] - mx); w[u] = e; ssum += e; }
    const float inv = 1.0f / ssum;

    // PV gather: (t+1) x 8 ds_read_b128, a-stride 65 f4 -> 8 bank-group spread
    float4 acc[8];
    #pragma unroll
    for (int j = 0; j < 8; ++j) acc[j] = make_float4(0.f, 0.f, 0.f, 0.f);
    #pragma unroll
    for (int u = 0; u < 8; ++u) if (u <= t) {        // wave-uniform trips
        const float pu = w[u];
        const float4* r = s4 + 378 + iu[u] * 65 + u * 8;
        #pragma unroll
        for (int j = 0; j < 8; ++j) {
            float4 m = r[j];
            acc[j].x = fmaf(pu, m.x, acc[j].x);
            acc[j].y = fmaf(pu, m.y, acc[j].y);
            acc[j].z = fmaf(pu, m.z, acc[j].z);
            acc[j].w = fmaf(pu, m.w, acc[j].w);
        }
    }
    // finalize: logits = acc*inv + bias (b128 broadcast)
    #pragma unroll
    for (int j = 0; j < 8; ++j) {
        float4 b = s4[370 + j];
        acc[j].x = fmaf(acc[j].x, inv, b.x);
        acc[j].y = fmaf(acc[j].y, inv, b.y);
        acc[j].z = fmaf(acc[j].z, inv, b.z);
        acc[j].w = fmaf(acc[j].w, inv, b.w);
    }
    __syncthreads();   // tables dead

    // stage all 512 rows: 8 ds_write_b128/thread, group-rotated (j+lb)&7
    {
        const int rbase4 = (lb * 8 + t) * 8;          // row base in float4 units
        #pragma unroll
        for (int j = 0; j < 8; ++j)
            s4[rbase4 + ((j + lb) & 7)] = acc[j];
    }
    __syncthreads();

    // de-swizzled copy-out: 512*29 = 14848 floats, coalesced scalar stores
    float* ob = out + (size_t)blk * (512 * NVOC);
    for (int i = tid; i < 512 * NVOC; i += 512) {
        const int rr = i / NVOC, v = i - rr * NVOC;
        ob[i] = s[rr * 32 + (((v >> 2) + (rr >> 3)) & 7) * 4 + (v & 3)];
    }
}

extern "C" void kernel_launch(void* const* d_in, const int* in_sizes, int n_in,
                              void* d_out, int out_size, void* d_ws, size_t ws_size,
                              hipStream_t stream) {
    const int* idx = (const int*)d_in[0];
    const void* tok = d_in[1];
    const void* pos = d_in[2];
    const void* Wk  = d_in[3];
    const void* Wq  = d_in[4];
    const void* Wv  = d_in[5];
    const void* lmW = d_in[6];
    const void* lmb = d_in[7];
    float* out = (float*)d_out;

    const int B = in_sizes[0] / 8;              // 131072
    const int nblk = B / 64;                    // 2048

    hipLaunchKernelGGL(prep_kernel, dim3(16), dim3(256), 0, stream,
                       tok, pos, Wk, Wq, Wv, lmW, lmb);
    hipLaunchKernelGGL(main_kernel, dim3(nblk), dim3(512), 0, stream,
                       idx, out);
}

// Round 7
// 166.883 us; speedup vs baseline: 1.1115x; 1.0080x over previous
//
#include <hip/hip_runtime.h>
#include <hip/hip_bf16.h>
#include <stdint.h>

// B=131072, T=8, E=16, V=29. f32 in / f32 out (proven round 4).
// g_tab layout (word offsets, float4-friendly):
//   QTT [29][32] @0      (a*32+c)
//   QTP [29][8]  @928    (a*8+u)
//   QPT [8][32]  @1160   (t*32+c)
//   QPP [8][8]   @1416   (t*8+u)
//   bias[32]     @1480
//   LM  [29]     @1512   a*260 + u*32 + v   (260%32=4 -> iu spreads 8 bank-groups)
//   total 9052 -> pad 9056 words (36224 B)
#define NVOC 29
#define TABW 9056

__device__ __attribute__((aligned(16))) float g_tab[TABW];

__device__ __forceinline__ float b2f(__hip_bfloat16 v) { return __bfloat162float(v); }
__device__ __forceinline__ float ldin(const void* p, int i, bool isf32) {
    return isf32 ? ((const float*)p)[i] : b2f(((const __hip_bfloat16*)p)[i]);
}

// ---------------- Kernel A: build tables once into g_tab ----------------
__global__ void prep_kernel(const void* __restrict__ tok, const void* __restrict__ pos,
                            const void* __restrict__ Wk,  const void* __restrict__ Wq,
                            const void* __restrict__ Wv,  const void* __restrict__ lmW,
                            const void* __restrict__ lmb) {
    __shared__ float sTQ[29][17], sTK[29][17], sTV[29][17];
    __shared__ float sPQ[8][17],  sPK[8][17],  sPV[8][17];
    __shared__ float sLW[29][17];
    const int tid = threadIdx.x;

    // input dtype sniff (insurance; inputs proven f32)
    const uint32_t* tw = (const uint32_t*)tok;
    int cnt = 0;
    #pragma unroll
    for (int wi = 0; wi < 32; ++wi) {
        uint32_t x = tw[wi];
        uint32_t e0 = (x >> 7) & 0xFF, e1 = (x >> 23) & 0xFF;
        cnt += (e0 >= 96 && e0 <= 132) ? 1 : 0;
        cnt += (e1 >= 96 && e1 <= 132) ? 1 : 0;
    }
    const bool isf32 = (cnt < 54);

    for (int i = tid; i < 29 * 16; i += 256) sLW[i >> 4][i & 15] = ldin(lmW, i, isf32);

    for (int i = tid; i < 111 * 16; i += 256) {
        const int h = i & 15, rt = i >> 4;
        const void* xp; int xo; const void* wp; float* dst;
        if (rt < 29)       { xp = tok; xo = rt * 16;         wp = Wq; dst = &sTQ[rt][h]; }
        else if (rt < 58)  { xp = tok; xo = (rt - 29) * 16;  wp = Wk; dst = &sTK[rt - 29][h]; }
        else if (rt < 87)  { xp = tok; xo = (rt - 58) * 16;  wp = Wv; dst = &sTV[rt - 58][h]; }
        else if (rt < 95)  { xp = pos; xo = (rt - 87) * 16;  wp = Wq; dst = &sPQ[rt - 87][h]; }
        else if (rt < 103) { xp = pos; xo = (rt - 95) * 16;  wp = Wk; dst = &sPK[rt - 95][h]; }
        else               { xp = pos; xo = (rt - 103) * 16; wp = Wv; dst = &sPV[rt - 103][h]; }
        float s = 0.f;
        if (isf32) {       // fast path: 8 dwordx4 loads instead of 32 scalar
            const float4* x4 = (const float4*)((const float*)xp + xo);
            const float4* w4 = (const float4*)((const float*)wp + h * 16);
            #pragma unroll
            for (int q = 0; q < 4; ++q) {
                float4 a = x4[q], b = w4[q];
                s += a.x * b.x + a.y * b.y + a.z * b.z + a.w * b.w;
            }
        } else {
            #pragma unroll
            for (int e = 0; e < 16; ++e)
                s += ldin(xp, xo + e, isf32) * ldin(wp, h * 16 + e, isf32);
        }
        *dst = s;
    }
    __syncthreads();

    const float f = 0.25f * 1.44269504088896340736f;  // scale * log2(e)

    for (int g = blockIdx.x * 256 + tid; g < TABW; g += gridDim.x * 256) {
        float val = 0.f;
        if (g < 928) {                       // QTT [29][32]
            int a = g >> 5, c = g & 31;
            if (c < 29) { float s = 0.f;
                #pragma unroll
                for (int h = 0; h < 16; ++h) s += sTQ[a][h] * sTK[c][h];
                val = f * s; }
        } else if (g < 1160) {               // QTP [29][8]
            int o = g - 928, a = o >> 3, u = o & 7; float s = 0.f;
            #pragma unroll
            for (int h = 0; h < 16; ++h) s += sTQ[a][h] * sPK[u][h];
            val = f * s;
        } else if (g < 1416) {               // QPT [8][32]
            int o = g - 1160, t = o >> 5, c = o & 31;
            if (c < 29) { float s = 0.f;
                #pragma unroll
                for (int h = 0; h < 16; ++h) s += sPQ[t][h] * sTK[c][h];
                val = f * s; }
        } else if (g < 1480) {               // QPP [8][8]
            int o = g - 1416, t = o >> 3, u = o & 7; float s = 0.f;
            #pragma unroll
            for (int h = 0; h < 16; ++h) s += sPQ[t][h] * sPK[u][h];
            val = f * s;
        } else if (g < 1512) {               // bias [32]
            int v = g - 1480;
            if (v < NVOC) val = ldin(lmb, v, isf32);
        } else if (g < 1512 + 29 * 260) {    // LM
            int o = g - 1512, a = o / 260, r = o % 260;
            if (r < 256) {
                int u = r >> 5, v = r & 31;
                if (v < NVOC) { float s = 0.f;
                    #pragma unroll
                    for (int h = 0; h < 16; ++h) s += (sTV[a][h] + sPV[u][h]) * sLW[v][h];
                    val = s; }
            }
        }
        g_tab[g] = val;
    }
}

// ---------------- Kernel B ----------------
// 256 threads = 32 batches x 8 t's. LDS = ONE 9056-word buffer (36.2 KB):
// tables first, then (tables dead) 256 output rows x 32 w staging overlaid.
// -> 4 blocks/CU, 32 waves/CU (2x round 6's occupancy) with the 128-VGPR
// budget of launch_bounds(256,4) -> no spills (round-5 lesson).
// t = tid>>5: each wave spans t in {2k,2k+1}; PV loop runs (t|1)+1 trips
// (wave-uniform), lanes with u>t contribute pu=0 (w[u] underflows to 0).
__global__ __launch_bounds__(256, 4)
void main_kernel(const int* __restrict__ idxg, float* __restrict__ out) {
    __shared__ __attribute__((aligned(16))) float s[TABW];   // 36224 B
    float4* s4 = (float4*)s;

    const int tid = threadIdx.x;
    const int blk = blockIdx.x;
    const int t  = tid >> 5;    // 0..7 (uniform per half-wave)
    const int lb = tid & 31;    // local batch 0..31

    // idx direct from global (8 t-threads share each 32 B -> L1 broadcast)
    const int4* ig = (const int4*)(idxg + (size_t)blk * 256);
    const int4 iA = ig[lb * 2], iB = ig[lb * 2 + 1];

    // stage tables as float4
    const float4* gt4 = (const float4*)g_tab;
    for (int i = tid; i < TABW / 4; i += 256) s4[i] = gt4[i];
    __syncthreads();

    const int iu[8] = { iA.x, iA.y, iA.z, iA.w, iB.x, iB.y, iB.z, iB.w };
    const int it = (t == 0) ? iu[0] : (t == 1) ? iu[1] : (t == 2) ? iu[2] :
                   (t == 3) ? iu[3] : (t == 4) ? iu[4] : (t == 5) ? iu[5] :
                   (t == 6) ? iu[6] : iu[7];

    // scores: QTP row (2 b128), QPP row (2 b128 bcast), QTT/QPT scalar gathers
    const float4 qtpA = s4[232 + it * 2], qtpB = s4[233 + it * 2];
    const float4 qppA = s4[354 + t * 2],  qppB = s4[355 + t * 2];
    const float qtp[8] = { qtpA.x, qtpA.y, qtpA.z, qtpA.w, qtpB.x, qtpB.y, qtpB.z, qtpB.w };
    const float qpp[8] = { qppA.x, qppA.y, qppA.z, qppA.w, qppB.x, qppB.y, qppB.z, qppB.w };

    float w[8];
    #pragma unroll
    for (int u = 0; u < 8; ++u) {
        float wu = s[it * 32 + iu[u]] + qtp[u]
                 + s[1160 + t * 32 + iu[u]] + qpp[u];
        w[u] = (u <= t) ? wu : -1.0e30f;     // exp2(-1e30) == 0
    }
    float mx = w[0];
    #pragma unroll
    for (int u = 1; u < 8; ++u) mx = fmaxf(mx, w[u]);
    float ssum = 0.f;
    #pragma unroll
    for (int u = 0; u < 8; ++u) { float e = exp2f(w[u] - mx); w[u] = e; ssum += e; }
    const float inv = 1.0f / ssum;

    // PV gather: (t|1)+1 wave-uniform trips x 8 ds_read_b128 (u>t lanes: pu==0)
    float4 acc[8];
    #pragma unroll
    for (int j = 0; j < 8; ++j) acc[j] = make_float4(0.f, 0.f, 0.f, 0.f);
    const int tmax = t | 1;
    #pragma unroll
    for (int u = 0; u < 8; ++u) if (u <= tmax) {
        const float pu = w[u];
        const float4* r = s4 + 378 + iu[u] * 65 + u * 8;
        #pragma unroll
        for (int j = 0; j < 8; ++j) {
            float4 m = r[j];
            acc[j].x = fmaf(pu, m.x, acc[j].x);
            acc[j].y = fmaf(pu, m.y, acc[j].y);
            acc[j].z = fmaf(pu, m.z, acc[j].z);
            acc[j].w = fmaf(pu, m.w, acc[j].w);
        }
    }
    // finalize: logits = acc*inv + bias (b128 broadcast)
    #pragma unroll
    for (int j = 0; j < 8; ++j) {
        float4 b = s4[370 + j];
        acc[j].x = fmaf(acc[j].x, inv, b.x);
        acc[j].y = fmaf(acc[j].y, inv, b.y);
        acc[j].z = fmaf(acc[j].z, inv, b.z);
        acc[j].w = fmaf(acc[j].w, inv, b.w);
    }
    __syncthreads();   // tables dead

    // stage 256 rows x 32 w (overlaid on tables): 8 ds_write_b128, rotation
    // (j+lb)&7 -> 8 words/bank = b128 minimum, conflict-free
    {
        const int rbase4 = (lb * 8 + t) * 8;
        #pragma unroll
        for (int j = 0; j < 8; ++j)
            s4[rbase4 + ((j + lb) & 7)] = acc[j];
    }
    __syncthreads();

    // de-swizzled copy-out: 256*29 = 7424 floats, coalesced scalar stores
    float* ob = out + (size_t)blk * (256 * NVOC);
    for (int i = tid; i < 256 * NVOC; i += 256) {
        const int rr = i / NVOC, v = i - rr * NVOC;
        ob[i] = s[rr * 32 + (((v >> 2) + (rr >> 3)) & 7) * 4 + (v & 3)];
    }
}

extern "C" void kernel_launch(void* const* d_in, const int* in_sizes, int n_in,
                              void* d_out, int out_size, void* d_ws, size_t ws_size,
                              hipStream_t stream) {
    const int* idx = (const int*)d_in[0];
    const void* tok = d_in[1];
    const void* pos = d_in[2];
    const void* Wk  = d_in[3];
    const void* Wq  = d_in[4];
    const void* Wv  = d_in[5];
    const void* lmW = d_in[6];
    const void* lmb = d_in[7];
    float* out = (float*)d_out;

    const int B = in_sizes[0] / 8;              // 131072
    const int nblk = B / 32;                    // 4096 blocks, 32 batches each

    hipLaunchKernelGGL(prep_kernel, dim3(16), dim3(256), 0, stream,
                       tok, pos, Wk, Wq, Wv, lmW, lmb);
    hipLaunchKernelGGL(main_kernel, dim3(nblk), dim3(256), 0, stream,
                       idx, out);
}